// Round 1
// baseline (87.236 us; speedup 1.0000x reference)
//
#include <hip/hip_runtime.h>

#define B_SZ 16384
#define N_SP 129
#define GRID 1024
#define BLOCK 256

typedef _Float16 half8 __attribute__((ext_vector_type(8)));
typedef float float4v __attribute__((ext_vector_type(4)));

// Persistent device-side tables — replaces ALL workspace usage (d_ws untouched,
// so the harness's 256 MB ws re-poison fill has nothing of ours to poison).
//   g_frag: 24 B-frags, 64 lanes x 8 f16 each;
//     frag = tbl*8 + t*4 + g (tbl: 0=tw 1=qxt 2=qtt_sym), element ((frag*64+lane)*8+j)
__device__ __align__(16) _Float16 g_frag[12288];
__device__ float g_twy[64];
__device__ float g_qxy[64];
__device__ float g_qyt[64];
__device__ float g_lint[64];
__device__ float g_liny_v;
__device__ float g_p1[GRID];
__device__ float g_p2[GRID];
__device__ unsigned g_ticket = 0;   // self-resetting: last block zeroes it each run

// index into main_w for quadratic pair (i<j), N=129: N + i*(2N-i-1)/2 + (j-i-1)
__device__ __forceinline__ int qidx(int i, int j) {
  return N_SP + i * (2 * N_SP - i - 1) / 2 + (j - i - 1);
}

// tanh(x) = 1 - 2/(e^{2x}+1): monotone, stable both tails
__device__ __forceinline__ float fast_tanh(float x) {
  float xc = fminf(fmaxf(x, -15.f), 15.f);
  float e = __expf(2.f * xc);
  return 1.f - 2.f / (e + 1.f);
}

__global__ void setup_kernel(const float* __restrict__ mw, const float* __restrict__ tw) {
  int t = blockIdx.x * blockDim.x + threadIdx.x;
  if (t < 12288) {
    int frag = t >> 9, e = t & 511;
    int lane = e >> 3, j = e & 7;
    int tbl = frag >> 3, tg = frag & 7;
    int kt = tg >> 2, g = tg & 3;
    int k = kt * 32 + (lane >> 4) * 8 + j;   // K index (d or u), 0..63
    int n = (lane & 15) + 16 * g;            // N index (unit or i), 0..63
    float v;
    if (tbl == 0) {
      v = tw[n * 65 + k];                    // B[k][n] = tw[n][k]
    } else if (tbl == 1) {
      v = mw[qidx(n, 65 + k)];               // Qxt[i=n][u=k]
    } else {
      v = 0.f;
      if (n != k) {
        int a = n < k ? n : k, b = n < k ? k : n;
        v = mw[qidx(65 + a, 65 + b)];        // Qtt_sym
      }
    }
    g_frag[t] = (_Float16)v;
  } else if (t < 12352) {
    int u = t - 12288; g_twy[u] = tw[u * 65 + 64];
  } else if (t < 12416) {
    int i = t - 12352; g_qxy[i] = mw[qidx(i, 64)];
  } else if (t < 12480) {
    int u = t - 12416; g_qyt[u] = mw[qidx(64, 65 + u)];
  } else if (t < 12544) {
    int u = t - 12480; g_lint[u] = mw[65 + u];
  } else if (t == 12544) {
    g_liny_v = mw[64];
  }
}

// 16 rows per block; 4 waves split the 64-unit dimension (wave wib owns
// units u = 16*wib + m). Shared x/dt tiles; B-frags staged into LDS via
// async global_load_lds (contiguous coalesced layout preserved — still
// defeats the R6-R8 register-sinking issue, now with zero staging VGPRs).
// Final penalty reduction folded into the last-arriving block (ticket),
// deterministic fixed-shape tree — no third kernel launch.
__global__ __launch_bounds__(BLOCK, 4) void main_kernel(
    const float* __restrict__ inps, const float* __restrict__ tb,
    float* __restrict__ out) {
  __shared__ __align__(16) _Float16 s_frag[12288];  // 24 KB, raw copy of g_frag
  __shared__ __align__(16) _Float16 s_x[1152];      // 16 rows x stride 72
  __shared__ __align__(16) _Float16 s_dt[1152];
  __shared__ float s_part[64];                      // 4 slices x 16 rows
  __shared__ float s_red[8];
  __shared__ bool s_last;

  const int tid = threadIdx.x;
  const int l = tid & 63, wib = tid >> 6;
  const int b0 = blockIdx.x << 4;   // 16 rows/block
  const int q = l >> 4, m = l & 15;
  const int u = (wib << 4) + m;     // this lane's unit / i index

  // ---- frag staging: async global->LDS, 6 x 16B per thread, contiguous ----
  {
    const char* src = (const char*)g_frag;
#pragma unroll
    for (int i = 0; i < 6; i++) {
      // LDS dest: wave-uniform base + lane*16 == byte (tid + 256*i)*16 (matches src)
      __builtin_amdgcn_global_load_lds(
          (const __attribute__((address_space(1))) void*)(src + (tid + 256 * i) * 16),
          (__attribute__((address_space(3))) void*)(s_frag + (wib * 64 + 256 * i) * 8),
          16, 0, 0);
    }
  }
  // ---- per-lane coefficient loads (L2-hot, issue early) ----
  const float twyv = g_twy[u];
  const float qxyv = g_qxy[u];
  const float qytv = g_qyt[u];
  const float lintv = g_lint[u];
  const float liny = g_liny_v;
  const float tbv = tb[u];

  // ---- x staging: 16 rows x 65 f32 = 260 float4 -> s_x f16 [16][72] ----
  {
    const float4* src4 = (const float4*)(inps + b0 * 65);  // 16B-aligned (4160 B/block)
    float4 v = src4[tid];
#pragma unroll
    for (int c = 0; c < 4; c++) {
      unsigned idx = tid * 4 + c;
      unsigned row = idx / 65u, col = idx - row * 65u;
      s_x[row * 72 + col] = (_Float16)((const float*)&v)[c];
    }
    if (tid < 4) {
      float4 v2 = src4[256 + tid];
#pragma unroll
      for (int c = 0; c < 4; c++) {
        unsigned idx = (256 + tid) * 4 + c;
        unsigned row = idx / 65u, col = idx - row * 65u;
        s_x[row * 72 + col] = (_Float16)((const float*)&v2)[c];
      }
    }
  }
  __syncthreads();  // compiler drains vmcnt(0) here -> global_load_lds complete

  const half8* fragv = (const half8*)s_frag;

  // A-frags of x (identical for all 4 waves): lane row m, k = t*32 + q*8 + j
  half8 ax0 = *(const half8*)(s_x + m * 72 + q * 8);
  half8 ax1 = *(const half8*)(s_x + m * 72 + 32 + q * 8);

  // matvec, unit-slice wib: C-layout (row=q*4+r, col=m -> unit u)
  float4v acc = {0.f, 0.f, 0.f, 0.f};
  acc = __builtin_amdgcn_mfma_f32_16x16x32_f16(ax0, fragv[(0 + wib) * 64 + l], acc, 0, 0, 0);
  acc = __builtin_amdgcn_mfma_f32_16x16x32_f16(ax1, fragv[(4 + wib) * 64 + l], acc, 0, 0, 0);

  // tanh pair + penalties; dt -> shared tile (all 64 units filled by 4 waves)
  float yv[4], dtv[4], stv[4];
  float pint = 0.f, pneut = 0.f;
#pragma unroll
  for (int r = 0; r < 4; r++) {
    yv[r] = (float)s_x[(q * 4 + r) * 72 + 64];
    float wpre = acc[r] + tbv;
    float w1 = wpre + twyv * yv[r];
    float w2 = wpre - twyv * yv[r];
    float t1 = fast_tanh(w1), t2 = fast_tanh(w2);
    dtv[r] = t1 - t2; stv[r] = t1 + t2;
    float a1 = 1.f - t1 * t1, a2 = 1.f - t2 * t2;
    pint += a1 * a1 + a2 * a2;
    float nv = t2 * w2 - t1 * w1;
    pneut += nv * nv;
    s_dt[(q * 4 + r) * 72 + u] = (_Float16)dtv[r];
  }
  __syncthreads();

  // A-frags of dt (full K=64, all rows valid)
  half8 ad0 = *(const half8*)(s_dt + m * 72 + q * 8);
  half8 ad1 = *(const half8*)(s_dt + m * 72 + 32 + q * 8);

  float4v rxt = {0.f, 0.f, 0.f, 0.f}, rtt = {0.f, 0.f, 0.f, 0.f};
  rxt = __builtin_amdgcn_mfma_f32_16x16x32_f16(ad0, fragv[(8 + wib) * 64 + l], rxt, 0, 0, 0);
  rxt = __builtin_amdgcn_mfma_f32_16x16x32_f16(ad1, fragv[(12 + wib) * 64 + l], rxt, 0, 0, 0);
  rtt = __builtin_amdgcn_mfma_f32_16x16x32_f16(ad0, fragv[(16 + wib) * 64 + l], rtt, 0, 0, 0);
  rtt = __builtin_amdgcn_mfma_f32_16x16x32_f16(ad1, fragv[(20 + wib) * 64 + l], rtt, 0, 0, 0);

  // per-(row, u) contribution; reduce over m (shfl), then over wib (LDS)
  float creg[4];
#pragma unroll
  for (int r = 0; r < 4; r++) {
    float xv = (float)s_x[(q * 4 + r) * 72 + u];
    float c = xv * (2.f * yv[r] * qxyv + rxt[r])
            + yv[r] * stv[r] * qytv
            + 0.5f * stv[r] * rtt[r]
            + lintv * dtv[r];
    c += __shfl_xor(c, 1); c += __shfl_xor(c, 2);
    c += __shfl_xor(c, 4); c += __shfl_xor(c, 8);
    creg[r] = c;
  }
  if (m == 0) {
#pragma unroll
    for (int r = 0; r < 4; r++) s_part[wib * 16 + q * 4 + r] = creg[r];
  }

  // penalties: wave reduce -> block partial (no float atomics, deterministic)
#pragma unroll
  for (int off = 1; off < 64; off <<= 1) {
    pint += __shfl_xor(pint, off);
    pneut += __shfl_xor(pneut, off);
  }
  if (l == 0) { s_red[wib] = pint; s_red[4 + wib] = pneut; }
  __syncthreads();

  if (tid < 16) {
    float c = s_part[tid] + s_part[16 + tid] + s_part[32 + tid] + s_part[48 + tid];
    float y = (float)s_x[tid * 72 + 64];
    out[b0 + tid] = 1.f + 2.f * y * liny + c;
  }
  if (tid == 0) {
    float bp1 = s_red[0] + s_red[1] + s_red[2] + s_red[3];
    float bp2 = s_red[4] + s_red[5] + s_red[6] + s_red[7];
    __hip_atomic_store(&g_p1[blockIdx.x], bp1, __ATOMIC_RELAXED, __HIP_MEMORY_SCOPE_AGENT);
    __hip_atomic_store(&g_p2[blockIdx.x], bp2, __ATOMIC_RELAXED, __HIP_MEMORY_SCOPE_AGENT);
    unsigned old = __hip_atomic_fetch_add(&g_ticket, 1u, __ATOMIC_ACQ_REL,
                                          __HIP_MEMORY_SCOPE_AGENT);
    s_last = (old == GRID - 1);
  }
  __syncthreads();

  // last-arriving block: deterministic fixed-shape final reduce (replaces
  // reduce_kernel launch). RMW-chain on g_ticket gives acquire of all g_p writes.
  if (s_last) {
    float a = 0.f, b = 0.f;
#pragma unroll
    for (int k = 0; k < 4; k++) {
      a += __hip_atomic_load(&g_p1[tid + 256 * k], __ATOMIC_RELAXED, __HIP_MEMORY_SCOPE_AGENT);
      b += __hip_atomic_load(&g_p2[tid + 256 * k], __ATOMIC_RELAXED, __HIP_MEMORY_SCOPE_AGENT);
    }
#pragma unroll
    for (int off = 1; off < 64; off <<= 1) {
      a += __shfl_xor(a, off);
      b += __shfl_xor(b, off);
    }
    if (l == 0) { s_part[wib] = a; s_part[4 + wib] = b; }
    __syncthreads();
    if (tid == 0) {
      out[B_SZ] = (s_part[0] + s_part[1] + s_part[2] + s_part[3]) * (1.f / 300.f);
      out[B_SZ + 1] = s_part[4] + s_part[5] + s_part[6] + s_part[7];
      __hip_atomic_store(&g_ticket, 0u, __ATOMIC_RELAXED, __HIP_MEMORY_SCOPE_AGENT);
    }
  }
}

extern "C" void kernel_launch(void* const* d_in, const int* in_sizes, int n_in,
                              void* d_out, int out_size, void* d_ws, size_t ws_size,
                              hipStream_t stream) {
  const float* inps = (const float*)d_in[0];
  const float* tw   = (const float*)d_in[1];
  const float* tb   = (const float*)d_in[2];
  const float* mw   = (const float*)d_in[3];
  float* out = (float*)d_out;
  (void)d_ws; (void)ws_size;  // workspace deliberately untouched
  setup_kernel<<<50, 256, 0, stream>>>(mw, tw);
  main_kernel<<<GRID, BLOCK, 0, stream>>>(inps, tb, out);
}

// Round 2
// 71.729 us; speedup vs baseline: 1.2162x; 1.2162x over previous
//
#include <hip/hip_runtime.h>

#define B_SZ 16384
#define N_SP 129
#define GRID 1024
#define BLOCK 256

typedef _Float16 half8 __attribute__((ext_vector_type(8)));
typedef float float4v __attribute__((ext_vector_type(4)));

// Only cross-kernel state: per-block penalty partials (device globals,
// d_ws untouched). Visibility main->reduce is via the dispatch boundary.
__device__ float g_p1[GRID];
__device__ float g_p2[GRID];

// index into main_w for quadratic pair (i<j), N=129: N + i*(2N-i-1)/2 + (j-i-1)
__device__ __forceinline__ int qidx(int i, int j) {
  return N_SP + i * (2 * N_SP - i - 1) / 2 + (j - i - 1);
}

// tanh(x) = 1 - 2/(e^{2x}+1): monotone, stable both tails
__device__ __forceinline__ float fast_tanh(float x) {
  float xc = fminf(fmaxf(x, -15.f), 15.f);
  float e = __expf(2.f * xc);
  return 1.f - 2.f / (e + 1.f);
}

// 16 rows per block; 4 waves split the 64-unit dimension (wave wib owns
// units u = 16*wib + m).
//
// Key structure change vs previous rounds: NO setup kernel, NO frag tables.
// Thread (wib, l) consumes exactly lane l of frags F = {wib,4+wib,...,20+wib},
// whose elements are closed-form gathers from tw/mw with n = u (this thread's
// unit) and k = kt*32 + q*8 + j. So the 6 B-fragments are built directly in
// registers from the L1-hot 33KB mw / 17KB tw tables — the whole
// setup->global->LDS->ds_read round-trip is deleted. All bf indices are
// compile-time constants after unroll (registers, not scratch).
__global__ __launch_bounds__(BLOCK, 4) void main_kernel(
    const float* __restrict__ inps, const float* __restrict__ tw,
    const float* __restrict__ tb, const float* __restrict__ mw,
    float* __restrict__ out) {
  __shared__ __align__(16) _Float16 s_x[1152];      // 16 rows x stride 72
  __shared__ __align__(16) _Float16 s_dt[1152];
  __shared__ float s_part[64];                      // 4 slices x 16 rows
  __shared__ float s_red[8];

  const int tid = threadIdx.x;
  const int l = tid & 63, wib = tid >> 6;
  const int b0 = blockIdx.x << 4;   // 16 rows/block
  const int q = l >> 4, m = l & 15;
  const int u = (wib << 4) + m;     // this lane's unit / i index

  // ---- x staging: 16 rows x 65 f32 = 260 float4 -> s_x f16 [16][72] ----
  {
    const float4* src4 = (const float4*)(inps + b0 * 65);  // 16B-aligned (4160 B/block)
    float4 v = src4[tid];
#pragma unroll
    for (int c = 0; c < 4; c++) {
      unsigned idx = tid * 4 + c;
      unsigned row = idx / 65u, col = idx - row * 65u;
      s_x[row * 72 + col] = (_Float16)((const float*)&v)[c];
    }
    if (tid < 4) {
      float4 v2 = src4[256 + tid];
#pragma unroll
      for (int c = 0; c < 4; c++) {
        unsigned idx = (256 + tid) * 4 + c;
        unsigned row = idx / 65u, col = idx - row * 65u;
        s_x[row * 72 + col] = (_Float16)((const float*)&v2)[c];
      }
    }
  }

  // ---- B-frag registers (6 x half8), gathered while s_x staging drains ----
  half8 bf0, bf1, bf2, bf3, bf4, bf5;
  {
    const int k0 = q * 8;        // kt=0 K-offset
    const int k1 = 32 + q * 8;   // kt=1 K-offset
    const int tw_base = u * 65;
    const int q1_base = qidx(u, 65);          // tbl1: contiguous in k
#pragma unroll
    for (int j = 0; j < 8; j++) bf0[j] = (_Float16)tw[tw_base + k0 + j];
#pragma unroll
    for (int j = 0; j < 8; j++) bf1[j] = (_Float16)tw[tw_base + k1 + j];
#pragma unroll
    for (int j = 0; j < 8; j++) bf2[j] = (_Float16)mw[q1_base + k0 + j];
#pragma unroll
    for (int j = 0; j < 8; j++) bf3[j] = (_Float16)mw[q1_base + k1 + j];
#pragma unroll
    for (int j = 0; j < 8; j++) {
      int k = k0 + j;
      int a = u < k ? u : k, b = u < k ? k : u;
      int idx = (u == k) ? 0 : qidx(65 + a, 65 + b);
      float v = mw[idx];
      bf4[j] = (_Float16)((u == k) ? 0.f : v);
    }
#pragma unroll
    for (int j = 0; j < 8; j++) {
      int k = k1 + j;
      int a = u < k ? u : k, b = u < k ? k : u;
      int idx = (u == k) ? 0 : qidx(65 + a, 65 + b);
      float v = mw[idx];
      bf5[j] = (_Float16)((u == k) ? 0.f : v);
    }
  }

  // ---- per-lane coefficients: direct closed-form loads (L1/L2-hot) ----
  const float twyv = tw[u * 65 + 64];
  const float qxyv = mw[qidx(u, 64)];
  const float qytv = mw[qidx(64, 65 + u)];
  const float lintv = mw[65 + u];
  const float liny = mw[64];
  const float tbv = tb[u];

  __syncthreads();  // s_x ready

  // A-frags of x (identical for all 4 waves): lane row m, k = t*32 + q*8 + j
  half8 ax0 = *(const half8*)(s_x + m * 72 + q * 8);
  half8 ax1 = *(const half8*)(s_x + m * 72 + 32 + q * 8);

  // matvec, unit-slice wib: C-layout (row=q*4+r, col=m -> unit u)
  float4v acc = {0.f, 0.f, 0.f, 0.f};
  acc = __builtin_amdgcn_mfma_f32_16x16x32_f16(ax0, bf0, acc, 0, 0, 0);
  acc = __builtin_amdgcn_mfma_f32_16x16x32_f16(ax1, bf1, acc, 0, 0, 0);

  // tanh pair + penalties; dt -> shared tile (all 64 units filled by 4 waves)
  float yv[4], dtv[4], stv[4];
  float pint = 0.f, pneut = 0.f;
#pragma unroll
  for (int r = 0; r < 4; r++) {
    yv[r] = (float)s_x[(q * 4 + r) * 72 + 64];
    float wpre = acc[r] + tbv;
    float w1 = wpre + twyv * yv[r];
    float w2 = wpre - twyv * yv[r];
    float t1 = fast_tanh(w1), t2 = fast_tanh(w2);
    dtv[r] = t1 - t2; stv[r] = t1 + t2;
    float a1 = 1.f - t1 * t1, a2 = 1.f - t2 * t2;
    pint += a1 * a1 + a2 * a2;
    float nv = t2 * w2 - t1 * w1;
    pneut += nv * nv;
    s_dt[(q * 4 + r) * 72 + u] = (_Float16)dtv[r];
  }
  __syncthreads();

  // A-frags of dt (full K=64, all rows valid)
  half8 ad0 = *(const half8*)(s_dt + m * 72 + q * 8);
  half8 ad1 = *(const half8*)(s_dt + m * 72 + 32 + q * 8);

  float4v rxt = {0.f, 0.f, 0.f, 0.f}, rtt = {0.f, 0.f, 0.f, 0.f};
  rxt = __builtin_amdgcn_mfma_f32_16x16x32_f16(ad0, bf2, rxt, 0, 0, 0);
  rxt = __builtin_amdgcn_mfma_f32_16x16x32_f16(ad1, bf3, rxt, 0, 0, 0);
  rtt = __builtin_amdgcn_mfma_f32_16x16x32_f16(ad0, bf4, rtt, 0, 0, 0);
  rtt = __builtin_amdgcn_mfma_f32_16x16x32_f16(ad1, bf5, rtt, 0, 0, 0);

  // per-(row, u) contribution; reduce over m (shfl), then over wib (LDS)
  float creg[4];
#pragma unroll
  for (int r = 0; r < 4; r++) {
    float xv = (float)s_x[(q * 4 + r) * 72 + u];
    float c = xv * (2.f * yv[r] * qxyv + rxt[r])
            + yv[r] * stv[r] * qytv
            + 0.5f * stv[r] * rtt[r]
            + lintv * dtv[r];
    c += __shfl_xor(c, 1); c += __shfl_xor(c, 2);
    c += __shfl_xor(c, 4); c += __shfl_xor(c, 8);
    creg[r] = c;
  }
  if (m == 0) {
#pragma unroll
    for (int r = 0; r < 4; r++) s_part[wib * 16 + q * 4 + r] = creg[r];
  }

  // penalties: wave reduce -> block partial (deterministic, no atomics)
#pragma unroll
  for (int off = 1; off < 64; off <<= 1) {
    pint += __shfl_xor(pint, off);
    pneut += __shfl_xor(pneut, off);
  }
  if (l == 0) { s_red[wib] = pint; s_red[4 + wib] = pneut; }
  __syncthreads();

  if (tid < 16) {
    float c = s_part[tid] + s_part[16 + tid] + s_part[32 + tid] + s_part[48 + tid];
    float y = (float)s_x[tid * 72 + 64];
    out[b0 + tid] = 1.f + 2.f * y * liny + c;
  }
  if (tid == 0) {
    g_p1[blockIdx.x] = s_red[0] + s_red[1] + s_red[2] + s_red[3];
    g_p2[blockIdx.x] = s_red[4] + s_red[5] + s_red[6] + s_red[7];
  }
}

__global__ __launch_bounds__(1024) void reduce_kernel(float* __restrict__ out) {
  __shared__ float s[32];
  const int tid = threadIdx.x;
  float a = g_p1[tid];
  float b = g_p2[tid];
#pragma unroll
  for (int off = 1; off < 64; off <<= 1) {
    a += __shfl_xor(a, off);
    b += __shfl_xor(b, off);
  }
  const int w = tid >> 6, l = tid & 63;
  if (l == 0) { s[w] = a; s[16 + w] = b; }
  __syncthreads();
  if (tid == 0) {
    float sa = 0.f, sb = 0.f;
#pragma unroll
    for (int i = 0; i < 16; i++) { sa += s[i]; sb += s[16 + i]; }
    out[B_SZ] = sa * (1.f / 300.f);
    out[B_SZ + 1] = sb;
  }
}

extern "C" void kernel_launch(void* const* d_in, const int* in_sizes, int n_in,
                              void* d_out, int out_size, void* d_ws, size_t ws_size,
                              hipStream_t stream) {
  const float* inps = (const float*)d_in[0];
  const float* tw   = (const float*)d_in[1];
  const float* tb   = (const float*)d_in[2];
  const float* mw   = (const float*)d_in[3];
  float* out = (float*)d_out;
  (void)d_ws; (void)ws_size;  // workspace deliberately untouched
  main_kernel<<<GRID, BLOCK, 0, stream>>>(inps, tw, tb, mw, out);
  reduce_kernel<<<1, 1024, 0, stream>>>(out);
}

// Round 3
// 71.364 us; speedup vs baseline: 1.2224x; 1.0051x over previous
//
#include <hip/hip_runtime.h>

#define B_SZ 16384
#define N_SP 129
#define GRID 1024
#define BLOCK 256

typedef _Float16 half8 __attribute__((ext_vector_type(8)));
typedef float float4v __attribute__((ext_vector_type(4)));

// Only cross-kernel state: per-block penalty partials (device globals,
// d_ws untouched). Visibility main->reduce is via the dispatch boundary.
__device__ float g_p1[GRID];
__device__ float g_p2[GRID];

// index into main_w for quadratic pair (i<j), N=129: N + i*(2N-i-1)/2 + (j-i-1)
__device__ __forceinline__ int qidx(int i, int j) {
  return N_SP + i * (2 * N_SP - i - 1) / 2 + (j - i - 1);
}

// tanh(x) = 1 - 2/(e^{2x}+1): monotone, stable both tails
__device__ __forceinline__ float fast_tanh(float x) {
  float xc = fminf(fmaxf(x, -15.f), 15.f);
  float e = __expf(2.f * xc);
  return 1.f - 2.f / (e + 1.f);
}

// 16 rows per block; 4 waves split the 64-unit dimension (wave wib owns
// units u = 16*wib + m).
//
// R3 structure: NO setup kernel AND NO scattered gathers. Each block builds
// the three B-operand tables in LDS from the raw inputs with coalesced
// loads, in layouts where every MFMA B-frag read is an aligned ds_read_b128:
//   s_tw [64][72] f16 : tw[u][k]            (float4-coalesced copy)
//   s_qxt[64][72] f16 : Qxt[i][k]=mw[qidx(i,65)+k]  (row-contiguous copy)
//   s_qtt[64][72] f16 : symmetric Qtt       (packed triangle -> scatter)
// Values are bit-identical to the old precomputed frag table.
__global__ __launch_bounds__(BLOCK, 4) void main_kernel(
    const float* __restrict__ inps, const float* __restrict__ tw,
    const float* __restrict__ tb, const float* __restrict__ mw,
    float* __restrict__ out) {
  __shared__ __align__(16) _Float16 s_tw[64 * 72];   // 9216 B
  __shared__ __align__(16) _Float16 s_qxt[64 * 72];  // 9216 B
  __shared__ __align__(16) _Float16 s_qtt[64 * 72];  // 9216 B
  __shared__ __align__(16) _Float16 s_x[1152];       // 16 rows x stride 72
  __shared__ __align__(16) _Float16 s_dt[1152];
  __shared__ float s_part[64];                       // 4 slices x 16 rows
  __shared__ float s_red[8];

  const int tid = threadIdx.x;
  const int l = tid & 63, wib = tid >> 6;
  const int b0 = blockIdx.x << 4;   // 16 rows/block
  const int q = l >> 4, m = l & 15;
  const int u = (wib << 4) + m;     // this lane's unit / i index

  // ---- x staging: 16 rows x 65 f32 = 260 float4 -> s_x f16 [16][72] ----
  {
    const float4* src4 = (const float4*)(inps + b0 * 65);  // 16B-aligned (4160 B/block)
    float4 v = src4[tid];
#pragma unroll
    for (int c = 0; c < 4; c++) {
      unsigned idx = tid * 4 + c;
      unsigned row = idx / 65u, col = idx - row * 65u;
      s_x[row * 72 + col] = (_Float16)((const float*)&v)[c];
    }
    if (tid < 4) {
      float4 v2 = src4[256 + tid];
#pragma unroll
      for (int c = 0; c < 4; c++) {
        unsigned idx = (256 + tid) * 4 + c;
        unsigned row = idx / 65u, col = idx - row * 65u;
        s_x[row * 72 + col] = (_Float16)((const float*)&v2)[c];
      }
    }
  }

  // ---- tw staging: 64x65 f32 = 1040 float4 -> s_tw [64][72] ----
  {
    const float4* src4 = (const float4*)tw;
#pragma unroll
    for (int s = 0; s < 4; s++) {
      float4 v = src4[tid + 256 * s];
#pragma unroll
      for (int c = 0; c < 4; c++) {
        unsigned idx = (tid + 256 * s) * 4 + c;
        unsigned row = idx / 65u, col = idx - row * 65u;
        s_tw[row * 72 + col] = (_Float16)((const float*)&v)[c];
      }
    }
    if (tid < 16) {
      float4 v = src4[1024 + tid];
#pragma unroll
      for (int c = 0; c < 4; c++) {
        unsigned idx = (1024 + tid) * 4 + c;
        unsigned row = idx / 65u, col = idx - row * 65u;
        s_tw[row * 72 + col] = (_Float16)((const float*)&v)[c];
      }
    }
  }

  // ---- qxt staging: 4096 elems, dst-linear (each wave = one contiguous row) ----
  // Qxt[i][k] = mw[qidx(i,65)+k]; qidx(i,65) = 193 + i*(257-i)/2 - i
  {
#pragma unroll
    for (int s = 0; s < 16; s++) {
      int d = tid + 256 * s;
      int i = d >> 6, k = d & 63;
      int src = 193 + ((i * (257 - i)) >> 1) - i + k;
      s_qxt[i * 72 + k] = (_Float16)mw[src];
    }
  }

  // ---- qtt staging: packed strict-upper triangle (2016 f32 at mw+6369),
  //      8 consecutive elems/thread, scatter to both (a,b) and (b,a) ----
  // row offset within triangle: off(a) = a*(127-a)/2, b = a+1+(p-off(a))
  {
    if (tid < 252) {
      const float* srcp = mw + 6369 + tid * 8;
      float v[8];
#pragma unroll
      for (int e = 0; e < 8; e++) v[e] = srcp[e];
      int p0 = tid * 8;
      int a = (int)((127.0f - sqrtf((float)(16129 - 8 * p0))) * 0.5f);
      if (a < 0) a = 0;
      if (a > 62) a = 62;
      while (a > 0 && (a * (127 - a)) / 2 > p0) --a;
      while (a < 62 && ((a + 1) * (126 - a)) / 2 <= p0) ++a;
      int b = a + 1 + (p0 - (a * (127 - a)) / 2);
#pragma unroll
      for (int e = 0; e < 8; e++) {
        _Float16 h = (_Float16)v[e];
        s_qtt[a * 72 + b] = h;
        s_qtt[b * 72 + a] = h;
        if (++b > 63) { ++a; b = a + 1; }
      }
    }
    if (tid < 64) s_qtt[tid * 72 + tid] = (_Float16)0.f;
  }

  // ---- per-lane coefficients: direct scalar loads (L2-hot, full f32) ----
  const float twyv = tw[u * 65 + 64];
  const float qxyv = mw[qidx(u, 64)];
  const float qytv = mw[qidx(64, 65 + u)];
  const float lintv = mw[65 + u];
  const float liny = mw[64];
  const float tbv = tb[u];

  __syncthreads();  // all LDS tables + s_x ready

  // A-frags of x (identical for all 4 waves): lane row m, k = t*32 + q*8 + j
  half8 ax0 = *(const half8*)(s_x + m * 72 + q * 8);
  half8 ax1 = *(const half8*)(s_x + m * 72 + 32 + q * 8);
  // B-frags: aligned ds_read_b128 from the staged tables (byte addr u*144+q*16)
  half8 bt0 = *(const half8*)(s_tw + u * 72 + q * 8);
  half8 bt1 = *(const half8*)(s_tw + u * 72 + 32 + q * 8);

  // matvec, unit-slice wib: C-layout (row=q*4+r, col=m -> unit u)
  float4v acc = {0.f, 0.f, 0.f, 0.f};
  acc = __builtin_amdgcn_mfma_f32_16x16x32_f16(ax0, bt0, acc, 0, 0, 0);
  acc = __builtin_amdgcn_mfma_f32_16x16x32_f16(ax1, bt1, acc, 0, 0, 0);

  // tanh pair + penalties; dt -> shared tile (all 64 units filled by 4 waves)
  float yv[4], dtv[4], stv[4];
  float pint = 0.f, pneut = 0.f;
#pragma unroll
  for (int r = 0; r < 4; r++) {
    yv[r] = (float)s_x[(q * 4 + r) * 72 + 64];
    float wpre = acc[r] + tbv;
    float w1 = wpre + twyv * yv[r];
    float w2 = wpre - twyv * yv[r];
    float t1 = fast_tanh(w1), t2 = fast_tanh(w2);
    dtv[r] = t1 - t2; stv[r] = t1 + t2;
    float a1 = 1.f - t1 * t1, a2 = 1.f - t2 * t2;
    pint += a1 * a1 + a2 * a2;
    float nv = t2 * w2 - t1 * w1;
    pneut += nv * nv;
    s_dt[(q * 4 + r) * 72 + u] = (_Float16)dtv[r];
  }
  __syncthreads();

  // A-frags of dt (full K=64, all rows valid)
  half8 ad0 = *(const half8*)(s_dt + m * 72 + q * 8);
  half8 ad1 = *(const half8*)(s_dt + m * 72 + 32 + q * 8);
  half8 bq0 = *(const half8*)(s_qxt + u * 72 + q * 8);
  half8 bq1 = *(const half8*)(s_qxt + u * 72 + 32 + q * 8);
  half8 bs0 = *(const half8*)(s_qtt + u * 72 + q * 8);
  half8 bs1 = *(const half8*)(s_qtt + u * 72 + 32 + q * 8);

  float4v rxt = {0.f, 0.f, 0.f, 0.f}, rtt = {0.f, 0.f, 0.f, 0.f};
  rxt = __builtin_amdgcn_mfma_f32_16x16x32_f16(ad0, bq0, rxt, 0, 0, 0);
  rxt = __builtin_amdgcn_mfma_f32_16x16x32_f16(ad1, bq1, rxt, 0, 0, 0);
  rtt = __builtin_amdgcn_mfma_f32_16x16x32_f16(ad0, bs0, rtt, 0, 0, 0);
  rtt = __builtin_amdgcn_mfma_f32_16x16x32_f16(ad1, bs1, rtt, 0, 0, 0);

  // per-(row, u) contribution; reduce over m (shfl), then over wib (LDS)
  float creg[4];
#pragma unroll
  for (int r = 0; r < 4; r++) {
    float xv = (float)s_x[(q * 4 + r) * 72 + u];
    float c = xv * (2.f * yv[r] * qxyv + rxt[r])
            + yv[r] * stv[r] * qytv
            + 0.5f * stv[r] * rtt[r]
            + lintv * dtv[r];
    c += __shfl_xor(c, 1); c += __shfl_xor(c, 2);
    c += __shfl_xor(c, 4); c += __shfl_xor(c, 8);
    creg[r] = c;
  }
  if (m == 0) {
#pragma unroll
    for (int r = 0; r < 4; r++) s_part[wib * 16 + q * 4 + r] = creg[r];
  }

  // penalties: wave reduce -> block partial (deterministic, no atomics)
#pragma unroll
  for (int off = 1; off < 64; off <<= 1) {
    pint += __shfl_xor(pint, off);
    pneut += __shfl_xor(pneut, off);
  }
  if (l == 0) { s_red[wib] = pint; s_red[4 + wib] = pneut; }
  __syncthreads();

  if (tid < 16) {
    float c = s_part[tid] + s_part[16 + tid] + s_part[32 + tid] + s_part[48 + tid];
    float y = (float)s_x[tid * 72 + 64];
    out[b0 + tid] = 1.f + 2.f * y * liny + c;
  }
  if (tid == 0) {
    g_p1[blockIdx.x] = s_red[0] + s_red[1] + s_red[2] + s_red[3];
    g_p2[blockIdx.x] = s_red[4] + s_red[5] + s_red[6] + s_red[7];
  }
}

__global__ __launch_bounds__(1024) void reduce_kernel(float* __restrict__ out) {
  __shared__ float s[32];
  const int tid = threadIdx.x;
  float a = g_p1[tid];
  float b = g_p2[tid];
#pragma unroll
  for (int off = 1; off < 64; off <<= 1) {
    a += __shfl_xor(a, off);
    b += __shfl_xor(b, off);
  }
  const int w = tid >> 6, l = tid & 63;
  if (l == 0) { s[w] = a; s[16 + w] = b; }
  __syncthreads();
  if (tid == 0) {
    float sa = 0.f, sb = 0.f;
#pragma unroll
    for (int i = 0; i < 16; i++) { sa += s[i]; sb += s[16 + i]; }
    out[B_SZ] = sa * (1.f / 300.f);
    out[B_SZ + 1] = sb;
  }
}

extern "C" void kernel_launch(void* const* d_in, const int* in_sizes, int n_in,
                              void* d_out, int out_size, void* d_ws, size_t ws_size,
                              hipStream_t stream) {
  const float* inps = (const float*)d_in[0];
  const float* tw   = (const float*)d_in[1];
  const float* tb   = (const float*)d_in[2];
  const float* mw   = (const float*)d_in[3];
  float* out = (float*)d_out;
  (void)d_ws; (void)ws_size;  // workspace deliberately untouched
  main_kernel<<<GRID, BLOCK, 0, stream>>>(inps, tw, tb, mw, out);
  reduce_kernel<<<1, 1024, 0, stream>>>(out);
}

// Round 4
// 69.165 us; speedup vs baseline: 1.2613x; 1.0318x over previous
//
#include <hip/hip_runtime.h>

#define B_SZ 16384
#define N_SP 129
#define GRID 512
#define BLOCK 256

typedef _Float16 half8 __attribute__((ext_vector_type(8)));
typedef float float4v __attribute__((ext_vector_type(4)));

// Only cross-kernel state: per-block penalty partials (device globals,
// d_ws untouched). Visibility main->reduce is via the dispatch boundary.
__device__ float g_p1[GRID];
__device__ float g_p2[GRID];

// index into main_w for quadratic pair (i<j), N=129: N + i*(2N-i-1)/2 + (j-i-1)
__device__ __forceinline__ int qidx(int i, int j) {
  return N_SP + i * (2 * N_SP - i - 1) / 2 + (j - i - 1);
}

// tanh(x) = 1 - 2/(e^{2x}+1): monotone, stable both tails
__device__ __forceinline__ float fast_tanh(float x) {
  float xc = fminf(fmaxf(x, -15.f), 15.f);
  float e = __expf(2.f * xc);
  return 1.f - 2.f / (e + 1.f);
}

// R4 structure: 512 blocks x 32 rows (2 blocks/CU). Each block stages the
// three B-operand tables ONCE (same bit-identical build as R3), then runs
// TWO 16-row tiles through a fused 2-phase pipeline:
//   stage everything -> barrier -> phase1 both tiles (matvec+tanh+dt) ->
//   barrier -> phase2 both tiles (4 matvecs + reductions) -> barrier -> out.
// Halves per-row staging traffic, barrier count, and block-launch count vs R3.
__global__ __launch_bounds__(BLOCK, 2) void main_kernel(
    const float* __restrict__ inps, const float* __restrict__ tw,
    const float* __restrict__ tb, const float* __restrict__ mw,
    float* __restrict__ out) {
  __shared__ __align__(16) _Float16 s_tw[64 * 72];   // 9216 B
  __shared__ __align__(16) _Float16 s_qxt[64 * 72];  // 9216 B
  __shared__ __align__(16) _Float16 s_qtt[64 * 72];  // 9216 B
  __shared__ __align__(16) _Float16 s_x[32 * 72];    // 32 rows x stride 72
  __shared__ __align__(16) _Float16 s_dt[32 * 72];
  __shared__ float s_part[128];                      // [tile][wib*16+row]
  __shared__ float s_red[8];

  const int tid = threadIdx.x;
  const int l = tid & 63, wib = tid >> 6;
  const int b0 = blockIdx.x << 5;   // 32 rows/block
  const int q = l >> 4, m = l & 15;
  const int u = (wib << 4) + m;     // this lane's unit / i index

  // ---- x staging: 32 rows x 65 f32 = 520 float4 -> s_x f16 [32][72] ----
  {
    const float4* src4 = (const float4*)(inps + b0 * 65);  // 8320 B/block, 16B-aligned
#pragma unroll
    for (int s = 0; s < 2; s++) {
      float4 v = src4[tid + 256 * s];
#pragma unroll
      for (int c = 0; c < 4; c++) {
        unsigned idx = (tid + 256 * s) * 4 + c;
        unsigned row = idx / 65u, col = idx - row * 65u;
        s_x[row * 72 + col] = (_Float16)((const float*)&v)[c];
      }
    }
    if (tid < 8) {
      float4 v = src4[512 + tid];
#pragma unroll
      for (int c = 0; c < 4; c++) {
        unsigned idx = (512 + tid) * 4 + c;
        unsigned row = idx / 65u, col = idx - row * 65u;
        s_x[row * 72 + col] = (_Float16)((const float*)&v)[c];
      }
    }
  }

  // ---- tw staging: 64x65 f32 = 1040 float4 -> s_tw [64][72] ----
  {
    const float4* src4 = (const float4*)tw;
#pragma unroll
    for (int s = 0; s < 4; s++) {
      float4 v = src4[tid + 256 * s];
#pragma unroll
      for (int c = 0; c < 4; c++) {
        unsigned idx = (tid + 256 * s) * 4 + c;
        unsigned row = idx / 65u, col = idx - row * 65u;
        s_tw[row * 72 + col] = (_Float16)((const float*)&v)[c];
      }
    }
    if (tid < 16) {
      float4 v = src4[1024 + tid];
#pragma unroll
      for (int c = 0; c < 4; c++) {
        unsigned idx = (1024 + tid) * 4 + c;
        unsigned row = idx / 65u, col = idx - row * 65u;
        s_tw[row * 72 + col] = (_Float16)((const float*)&v)[c];
      }
    }
  }

  // ---- qxt staging: 4096 elems, dst-linear (each wave = one contiguous row) ----
  // Qxt[i][k] = mw[qidx(i,65)+k]; qidx(i,65) = 193 + i*(257-i)/2 - i
  {
#pragma unroll
    for (int s = 0; s < 16; s++) {
      int d = tid + 256 * s;
      int i = d >> 6, k = d & 63;
      int src = 193 + ((i * (257 - i)) >> 1) - i + k;
      s_qxt[i * 72 + k] = (_Float16)mw[src];
    }
  }

  // ---- qtt staging: packed strict-upper triangle (2016 f32 at mw+6369),
  //      8 consecutive elems/thread, scatter to both (a,b) and (b,a) ----
  {
    if (tid < 252) {
      const float* srcp = mw + 6369 + tid * 8;
      float v[8];
#pragma unroll
      for (int e = 0; e < 8; e++) v[e] = srcp[e];
      int p0 = tid * 8;
      int a = (int)((127.0f - sqrtf((float)(16129 - 8 * p0))) * 0.5f);
      if (a < 0) a = 0;
      if (a > 62) a = 62;
      while (a > 0 && (a * (127 - a)) / 2 > p0) --a;
      while (a < 62 && ((a + 1) * (126 - a)) / 2 <= p0) ++a;
      int b = a + 1 + (p0 - (a * (127 - a)) / 2);
#pragma unroll
      for (int e = 0; e < 8; e++) {
        _Float16 h = (_Float16)v[e];
        s_qtt[a * 72 + b] = h;
        s_qtt[b * 72 + a] = h;
        if (++b > 63) { ++a; b = a + 1; }
      }
    }
    if (tid < 64) s_qtt[tid * 72 + tid] = (_Float16)0.f;
  }

  // ---- per-lane coefficients: direct scalar loads (full f32) ----
  const float twyv = tw[u * 65 + 64];
  const float qxyv = mw[qidx(u, 64)];
  const float qytv = mw[qidx(64, 65 + u)];
  const float lintv = mw[65 + u];
  const float liny = mw[64];
  const float tbv = tb[u];

  __syncthreads();  // all LDS tables + both x tiles ready

  // B-frags for phase 1 (shared by both tiles)
  half8 bt0 = *(const half8*)(s_tw + u * 72 + q * 8);
  half8 bt1 = *(const half8*)(s_tw + u * 72 + 32 + q * 8);

  // ---- phase 1: both tiles — first matvec, tanh pair, dt tiles, penalties ----
  float yv[2][4], dtv[2][4], stv[2][4];
  float pint = 0.f, pneut = 0.f;
#pragma unroll
  for (int it = 0; it < 2; it++) {
    const int rb = it << 4;
    half8 ax0 = *(const half8*)(s_x + (rb + m) * 72 + q * 8);
    half8 ax1 = *(const half8*)(s_x + (rb + m) * 72 + 32 + q * 8);
    float4v acc = {0.f, 0.f, 0.f, 0.f};
    acc = __builtin_amdgcn_mfma_f32_16x16x32_f16(ax0, bt0, acc, 0, 0, 0);
    acc = __builtin_amdgcn_mfma_f32_16x16x32_f16(ax1, bt1, acc, 0, 0, 0);
#pragma unroll
    for (int r = 0; r < 4; r++) {
      yv[it][r] = (float)s_x[(rb + q * 4 + r) * 72 + 64];
      float wpre = acc[r] + tbv;
      float w1 = wpre + twyv * yv[it][r];
      float w2 = wpre - twyv * yv[it][r];
      float t1 = fast_tanh(w1), t2 = fast_tanh(w2);
      dtv[it][r] = t1 - t2; stv[it][r] = t1 + t2;
      float a1 = 1.f - t1 * t1, a2 = 1.f - t2 * t2;
      pint += a1 * a1 + a2 * a2;
      float nv = t2 * w2 - t1 * w1;
      pneut += nv * nv;
      s_dt[(rb + q * 4 + r) * 72 + u] = (_Float16)dtv[it][r];
    }
  }
  __syncthreads();

  // B-frags for phase 2 (shared by both tiles)
  half8 bq0 = *(const half8*)(s_qxt + u * 72 + q * 8);
  half8 bq1 = *(const half8*)(s_qxt + u * 72 + 32 + q * 8);
  half8 bs0 = *(const half8*)(s_qtt + u * 72 + q * 8);
  half8 bs1 = *(const half8*)(s_qtt + u * 72 + 32 + q * 8);

  // ---- phase 2: both tiles — 4 matvecs each, per-row contributions ----
#pragma unroll
  for (int it = 0; it < 2; it++) {
    const int rb = it << 4;
    half8 ad0 = *(const half8*)(s_dt + (rb + m) * 72 + q * 8);
    half8 ad1 = *(const half8*)(s_dt + (rb + m) * 72 + 32 + q * 8);
    float4v rxt = {0.f, 0.f, 0.f, 0.f}, rtt = {0.f, 0.f, 0.f, 0.f};
    rxt = __builtin_amdgcn_mfma_f32_16x16x32_f16(ad0, bq0, rxt, 0, 0, 0);
    rxt = __builtin_amdgcn_mfma_f32_16x16x32_f16(ad1, bq1, rxt, 0, 0, 0);
    rtt = __builtin_amdgcn_mfma_f32_16x16x32_f16(ad0, bs0, rtt, 0, 0, 0);
    rtt = __builtin_amdgcn_mfma_f32_16x16x32_f16(ad1, bs1, rtt, 0, 0, 0);
#pragma unroll
    for (int r = 0; r < 4; r++) {
      float xv = (float)s_x[(rb + q * 4 + r) * 72 + u];
      float c = xv * (2.f * yv[it][r] * qxyv + rxt[r])
              + yv[it][r] * stv[it][r] * qytv
              + 0.5f * stv[it][r] * rtt[r]
              + lintv * dtv[it][r];
      c += __shfl_xor(c, 1); c += __shfl_xor(c, 2);
      c += __shfl_xor(c, 4); c += __shfl_xor(c, 8);
      if (m == 0) s_part[it * 64 + wib * 16 + q * 4 + r] = c;
    }
  }

  // penalties: one wave reduce across both tiles -> block partial
#pragma unroll
  for (int off = 1; off < 64; off <<= 1) {
    pint += __shfl_xor(pint, off);
    pneut += __shfl_xor(pneut, off);
  }
  if (l == 0) { s_red[wib] = pint; s_red[4 + wib] = pneut; }
  __syncthreads();

  if (tid < 32) {
    const int it = tid >> 4, t = tid & 15;
    float c = s_part[it * 64 + t] + s_part[it * 64 + 16 + t]
            + s_part[it * 64 + 32 + t] + s_part[it * 64 + 48 + t];
    float y = (float)s_x[(it * 16 + t) * 72 + 64];
    out[b0 + it * 16 + t] = 1.f + 2.f * y * liny + c;
  }
  if (tid == 0) {
    g_p1[blockIdx.x] = s_red[0] + s_red[1] + s_red[2] + s_red[3];
    g_p2[blockIdx.x] = s_red[4] + s_red[5] + s_red[6] + s_red[7];
  }
}

__global__ __launch_bounds__(512) void reduce_kernel(float* __restrict__ out) {
  __shared__ float s[16];
  const int tid = threadIdx.x;
  float a = g_p1[tid];
  float b = g_p2[tid];
#pragma unroll
  for (int off = 1; off < 64; off <<= 1) {
    a += __shfl_xor(a, off);
    b += __shfl_xor(b, off);
  }
  const int w = tid >> 6, l = tid & 63;
  if (l == 0) { s[w] = a; s[8 + w] = b; }
  __syncthreads();
  if (tid == 0) {
    float sa = 0.f, sb = 0.f;
#pragma unroll
    for (int i = 0; i < 8; i++) { sa += s[i]; sb += s[8 + i]; }
    out[B_SZ] = sa * (1.f / 300.f);
    out[B_SZ + 1] = sb;
  }
}

extern "C" void kernel_launch(void* const* d_in, const int* in_sizes, int n_in,
                              void* d_out, int out_size, void* d_ws, size_t ws_size,
                              hipStream_t stream) {
  const float* inps = (const float*)d_in[0];
  const float* tw   = (const float*)d_in[1];
  const float* tb   = (const float*)d_in[2];
  const float* mw   = (const float*)d_in[3];
  float* out = (float*)d_out;
  (void)d_ws; (void)ws_size;  // workspace deliberately untouched
  main_kernel<<<GRID, BLOCK, 0, stream>>>(inps, tw, tb, mw, out);
  reduce_kernel<<<1, 512, 0, stream>>>(out);
}